// Round 3
// baseline (119.346 us; speedup 1.0000x reference)
//
#include <hip/hip_runtime.h>
#include <math.h>

#define T_IN 64
#define NPIX 16384
#define MAX_ITER 10
#define NSLOT 43

typedef _Float16 half8_t __attribute__((ext_vector_type(8)));
typedef __fp16   fp16x2  __attribute__((ext_vector_type(2)));
typedef float    f32x4   __attribute__((ext_vector_type(4)));
typedef int      i32x4   __attribute__((ext_vector_type(4)));

union H8 { half8_t v; fp16x2 h2[4]; i32x4 i4; };

__device__ __forceinline__ float rcp_fast(float x) { return __builtin_amdgcn_rcpf(x); }

__constant__ constexpr int NTMIN[16]  = {0,0,0,0,0,1,1,1,1,2,2,2,2,3,3,3};
__constant__ constexpr int TOFS[16]   = {0,4,8,12,16,20,23,26,29,32,34,36,38,40,41,42};
__constant__ constexpr int LASTKT[4]  = {4,8,12,15};   // last kt where nt is active

// ---- field build for tile KT (compile-time KT -> all array idx constant) ----
template<int KT>
__device__ __forceinline__ void buildTile(float T0, float nK, float r, int q,
        const float (&d10b)[16], const float (&tse0)[8], const float (&tse15)[8],
        H8& F0h, H8& F1h, H8& F2h) {
    float  x[8];
    fp16x2 d1h[4];
    float  d10 = T0 - d10b[KT];
    const fp16x2 c1 = {(__fp16)0.25f, (__fp16)0.25f};
    const fp16x2 c2 = {(__fp16)0.50f, (__fp16)0.50f};
    const fp16x2 c3 = {(__fp16)0.75f, (__fp16)0.75f};
    bool arith = true;
    if constexpr (KT == 0 || KT == 15) {
        bool flat = (KT == 0) ? (q == 0) : (q == 3);   // clamped tsh samples
        if (flat) {
            arith = false;
            const float* te;
            if constexpr (KT == 0) te = tse0; else te = tse15;
            #pragma unroll
            for (int j = 0; j < 8; ++j) x[j] = __expf(nK * (T0 - te[j]));
            #pragma unroll
            for (int jj = 0; jj < 4; ++jj)
                d1h[jj] = __builtin_amdgcn_cvt_pkrtz(T0 - te[2*jj],
                                                     T0 - te[2*jj+1]);
        }
    }
    if (arith) {   // arithmetic tsh (step 0.125): split chains + pk d1h rebuild
        x[0] = __expf(nK * d10);
        x[4] = __expf(nK * (d10 - 0.5f));
        x[1] = x[0]*r; x[2] = x[1]*r; x[3] = x[2]*r;
        x[5] = x[4]*r; x[6] = x[5]*r; x[7] = x[6]*r;
        fp16x2 D0 = __builtin_amdgcn_cvt_pkrtz(d10, d10 - 0.125f);
        d1h[0] = D0;
        d1h[1] = D0 - c1;
        d1h[2] = D0 - c2;
        d1h[3] = D0 - c3;
    }
    #pragma unroll
    for (int jj = 0; jj < 4; ++jj) {
        float s1a = rcp_fast(1.0f + x[2*jj]);
        float s1b = rcp_fast(1.0f + x[2*jj+1]);
        fp16x2 sh = __builtin_amdgcn_cvt_pkrtz(s1a, s1b);
        fp16x2 eh = sh - sh*sh;                  // v_pk f16
        F0h.h2[jj] = sh;
        F1h.h2[jj] = eh * d1h[jj];
        F2h.h2[jj] = eh;
    }
}

// ---- nt-quadrant split pipeline: H=0 owns nt{0,3}, H=1 owns nt{1,2}. ----
// Each wave's acc is the COMPLETE conv sum for its quadrants -> no acc
// exchange. Build kt+1 while MFMA kt (stride-1 ping-pong).
template<int H, int KT>
struct PipeN {
    static constexpr int NA   = (H == 0) ? 0 : 1;
    static constexpr int NB   = (H == 0) ? 3 : 2;
    static constexpr int LAST = (H == 0) ? 15 : 12;
    static __device__ __forceinline__ void run(float T0, float nK, float r, int q, int lane,
            const float (&d10b)[16], const float (&tse0)[8], const float (&tse15)[8],
            const i32x4* __restrict__ Bs,
            H8 (&F0p)[2], H8 (&F1p)[2], H8 (&F2p)[2],
            f32x4 (&acc)[3][2]) {
        constexpr int PB = KT & 1;
        if constexpr (KT + 1 <= LAST)
            buildTile<KT+1>(T0, nK, r, q, d10b, tse0, tse15,
                            F0p[PB^1], F1p[PB^1], F2p[PB^1]);
        const f32x4 Z = (f32x4){0.f, 0.f, 0.f, 0.f};
        if constexpr (KT <= LASTKT[NA]) {
            constexpr int slot = TOFS[KT] + NA - NTMIN[KT];
            H8 bh; bh.i4 = Bs[slot*64 + lane];
            if constexpr (KT == 0) {
                acc[0][0] = __builtin_amdgcn_mfma_f32_16x16x32_f16(F0p[PB].v, bh.v, Z, 0, 0, 0);
                acc[1][0] = __builtin_amdgcn_mfma_f32_16x16x32_f16(F1p[PB].v, bh.v, Z, 0, 0, 0);
                acc[2][0] = __builtin_amdgcn_mfma_f32_16x16x32_f16(F2p[PB].v, bh.v, Z, 0, 0, 0);
            } else {
                acc[0][0] = __builtin_amdgcn_mfma_f32_16x16x32_f16(F0p[PB].v, bh.v, acc[0][0], 0, 0, 0);
                acc[1][0] = __builtin_amdgcn_mfma_f32_16x16x32_f16(F1p[PB].v, bh.v, acc[1][0], 0, 0, 0);
                acc[2][0] = __builtin_amdgcn_mfma_f32_16x16x32_f16(F2p[PB].v, bh.v, acc[2][0], 0, 0, 0);
            }
        }
        if constexpr (KT <= LASTKT[NB]) {
            constexpr int slot = TOFS[KT] + NB - NTMIN[KT];
            H8 bh; bh.i4 = Bs[slot*64 + lane];
            if constexpr (KT == 0) {
                acc[0][1] = __builtin_amdgcn_mfma_f32_16x16x32_f16(F0p[PB].v, bh.v, Z, 0, 0, 0);
                acc[1][1] = __builtin_amdgcn_mfma_f32_16x16x32_f16(F1p[PB].v, bh.v, Z, 0, 0, 0);
                acc[2][1] = __builtin_amdgcn_mfma_f32_16x16x32_f16(F2p[PB].v, bh.v, Z, 0, 0, 0);
            } else {
                acc[0][1] = __builtin_amdgcn_mfma_f32_16x16x32_f16(F0p[PB].v, bh.v, acc[0][1], 0, 0, 0);
                acc[1][1] = __builtin_amdgcn_mfma_f32_16x16x32_f16(F1p[PB].v, bh.v, acc[1][1], 0, 0, 0);
                acc[2][1] = __builtin_amdgcn_mfma_f32_16x16x32_f16(F2p[PB].v, bh.v, acc[2][1], 0, 0, 0);
            }
        }
        if constexpr (KT + 1 <= LAST)
            PipeN<H, KT+1>::run(T0, nK, r, q, lane, d10b, tse0, tse15, Bs, F0p, F1p, F2p, acc);
    }
};

template<int H>
__device__ __forceinline__ void pipeAcc(float T0, float nK, float r, int q, int lane,
        const float (&d10b)[16], const float (&tse0)[8], const float (&tse15)[8],
        const i32x4* __restrict__ Bs, f32x4 (&acc)[3][2]) {
    H8 F0p[2], F1p[2], F2p[2];
    buildTile<0>(T0, nK, r, q, d10b, tse0, tse15, F0p[0], F1p[0], F2p[0]);
    PipeN<H, 0>::run(T0, nK, r, q, lane, d10b, tse0, tse15, Bs, F0p, F1p, F2p, acc);
}

// ---------------------------------------------------------------- prep ------
// Unchanged from R16: phase A + C_dc/C_nn partials; B built once -> global ws.
__global__ __launch_bounds__(256, 1) void k_prep(
        const float* __restrict__ ctc,  const float* __restrict__ aif,
        const float* __restrict__ timev,const float* __restrict__ eta,
        float* __restrict__ tshg, i32x4* __restrict__ Bg,
        f32x4* __restrict__ partials) {
    __shared__ float tshs[512];
    __shared__ float aifos[512];
    __shared__ float a_s[64], t_s[64];
    __shared__ f32x4 red[4];

    const int tid  = threadIdx.x;
    const int lane = tid & 63;
    const int wid  = tid >> 6;
    const int q = lane >> 4, n = lane & 15;
    const int pixbase = blockIdx.x * 64 + wid * 16;
    const int mypix   = pixbase + n;

    if (tid < 64) { a_s[tid] = aif[tid]; t_s[tid] = timev[tid]; }
    float A  = eta[mypix];
    float K  = eta[NPIX + mypix];
    float T0 = eta[2*NPIX + mypix];
    __syncthreads();
    {
        float m5a = 0.2f * (a_s[0]+a_s[1]+a_s[2]+a_s[3]+a_s[4]);
        float t16;
        {   // t_os[16]: x = (16-3.5)/8 = 1.5625
            float xx = 1.5625f; int i0 = (int)xx; float f = xx - (float)i0;
            t16 = t_s[i0]*(1.0f-f) + t_s[i0+1]*f;
        }
        #pragma unroll
        for (int rep = 0; rep < 2; ++rep) {
            int i = tid + 256*rep;
            float x = ((float)i - 3.5f) * 0.125f;
            float ao, to;
            if (x <= 0.0f)       { ao = a_s[0]  - m5a; to = t_s[0];  }
            else if (x >= 63.0f) { ao = a_s[63] - m5a; to = t_s[63]; }
            else {
                int i0 = (int)x; float f = x - (float)i0;
                ao = (a_s[i0]-m5a)*(1.0f-f) + (a_s[i0+1]-m5a)*f;
                to = t_s[i0]*(1.0f-f) + t_s[i0+1]*f;
            }
            aifos[i] = ao;
            tshs[i]  = to - t16;
            if (blockIdx.x == 0) tshg[i] = to - t16;
        }
    }
    __syncthreads();

    // ---- B tile build: block s (< NSLOT) computes slot s, threads 0..63 ----
    if (blockIdx.x < NSLOT && tid < 64) {
        int slot = blockIdx.x, l = tid;
        int kt, nt;
        if (slot < 20)      { kt = slot >> 2; nt = slot & 3; }
        else if (slot < 32) { int s = slot - 20; int d3 = s / 3; kt = 5 + d3; nt = 1 + (s - 3*d3); }
        else if (slot < 40) { int s = slot - 32; kt = 9 + (s >> 1); nt = 2 + (s & 1); }
        else                { kt = 13 + (slot - 40); nt = 3; }
        int kbase = 32*kt + 8*(l >> 4);
        int m = 16 + 8 * (16*nt + (l & 15));   // m_d = 16+8d
        H8 bh;
        #pragma unroll
        for (int jj = 0; jj < 4; ++jj) {
            float v[2];
            #pragma unroll
            for (int h = 0; h < 2; ++h) {
                int k  = kbase + 2*jj + h;
                int ai = m - k;
                float s2 = 1.0f / (1.0f + __expf(-500.0f * tshs[k]));
                v[h] = (ai >= 0 && ai < 512) ? s2 * aifos[ai] * 0.125f : 0.0f;
            }
            bh.h2[jj] = (fp16x2){(__fp16)v[0], (__fp16)v[1]};   // RTN
        }
        Bg[slot*64 + l] = bh.i4;
    }

    // ---- ctc_dc partials ----
    float vs = 0.f;
    #pragma unroll
    for (int reg = 0; reg < 4; ++reg) {
        const float* cp = ctc + (pixbase + q*4 + reg) * T_IN;
        float m5 = 0.2f * (cp[0]+cp[1]+cp[2]+cp[3]+cp[4]);
        #pragma unroll
        for (int nt = 0; nt < 4; ++nt) {
            int d = nt*16 + n;
            float cc = cp[d] - m5;
            float cm = cp[(d > 0) ? d-1 : 0] - m5;
            float dc = (d == 0) ? cc : (0.4375f*cm + 0.5625f*cc);
            vs += dc * dc;
        }
    }
    {
        f32x4 pv = (f32x4){vs, 0.25f*A*A, 0.25f*K*K, 0.25f*T0*T0};
        #pragma unroll
        for (int m = 1; m < 64; m <<= 1) {
            pv.x += __shfl_xor(pv.x, m); pv.y += __shfl_xor(pv.y, m);
            pv.z += __shfl_xor(pv.z, m); pv.w += __shfl_xor(pv.w, m);
        }
        if (lane == 0) red[wid] = pv;
    }
    __syncthreads();
    if (tid == 0)
        partials[blockIdx.x] = red[0] + red[1] + red[2] + red[3];
}

// ---------------------------------------------------------------- iter ------
// R17: nt-quadrant wave split, 512 blocks x 256 thr (2 pairs) -> 2 independent
// blocks/CU (decorrelated waves/SIMD). One barrier/iter; dot-partial exchange
// is 12 scalars per q-group, double-buffered by iteration parity.
__global__ __launch_bounds__(256, 2) void k_iter(
        const float* __restrict__ ctc,  const float* __restrict__ lam,
        const float* __restrict__ eta,  const float* __restrict__ tshg,
        const i32x4* __restrict__ Bg,   const f32x4* __restrict__ partials,
        float* __restrict__ out) {
    __shared__ i32x4 Bs[NSLOT * 64];        // 43 KB
    __shared__ float tshs[512];             // 2 KB
    __shared__ float xs[2][2][2][4][12];    // [itbuf][pair][hh][q][12] = 1.5 KB

    const int tid  = threadIdx.x;
    const int lane = tid & 63;
    const int wid  = tid >> 6;         // 0..3
    const int hh   = wid & 1;          // nt-half handled by this wave
    const int pairid = wid >> 1;       // pixel group 0..1
    const int q = lane >> 4, n = lane & 15;
    const int pixbase = blockIdx.x * 32 + pairid * 16;
    const int mypix   = pixbase + n;

    // ---- stage B + tshs into LDS ----
    for (int idx = tid; idx < NSLOT * 64; idx += 256) Bs[idx] = Bg[idx];
    tshs[tid] = tshg[tid];
    if (tid < 256) tshs[tid + 256] = tshg[tid + 256];

    float A  = eta[mypix];
    float K  = eta[NPIX + mypix];
    float T0 = eta[2*NPIX + mypix];
    const float pA = A, pK = K, pT = T0;

    // nt quadrants owned by this wave
    const int ntA = hh ? 1 : 0;
    const int ntB = hh ? 2 : 3;

    // ctc_dc: dcreg[L][reg] = dc[p=q*4+reg][d=nt(L)*16+n]
    float dcreg[2][4];
    #pragma unroll
    for (int reg = 0; reg < 4; ++reg) {
        const float* cp = ctc + (pixbase + q*4 + reg) * T_IN;
        float m5 = 0.2f * (cp[0]+cp[1]+cp[2]+cp[3]+cp[4]);
        #pragma unroll
        for (int L = 0; L < 2; ++L) {
            int nt = L ? ntB : ntA;
            int d = nt*16 + n;
            float cc = cp[d] - m5;
            float cm = cp[(d > 0) ? d-1 : 0] - m5;
            dcreg[L][reg] = (d == 0) ? cc : (0.4375f*cm + 0.5625f*cc);
        }
    }

    // ---- reduce the 256 completed partials ----
    f32x4 tot = partials[lane] + partials[64+lane] + partials[128+lane]
              + partials[192+lane];
    #pragma unroll
    for (int m = 1; m < 64; m <<= 1) {
        tot.x += __shfl_xor(tot.x, m); tot.y += __shfl_xor(tot.y, m);
        tot.z += __shfl_xor(tot.z, m); tot.w += __shfl_xor(tot.w, m);
    }
    float spl;
    {
        float xl = lam[0];
        spl = (xl > 0.0f) ? (xl + log1pf(__expf(-xl))) : log1pf(__expf(xl));
    }
    const float cdc2 = 2.0f / tot.x;
    const float rgA  = 2.0f * spl / tot.y;
    const float rgK  = 2.0f * spl / tot.z;
    const float rgT  = 2.0f * spl / tot.w;

    __syncthreads();   // Bs / tshs visible

    // ---- hoist tsh seeds (iteration-invariant, per-lane q) ----
    float  d10b[16];           // chain seeds: tsh[32kt+8q]
    float  tse0[8], tse15[8];  // full f32 for the edge path
    #pragma unroll
    for (int kt = 0; kt < 16; ++kt) d10b[kt] = tshs[32*kt + 8*q];
    #pragma unroll
    for (int j = 0; j < 8; ++j) { tse0[j] = tshs[8*q + j]; tse15[j] = tshs[480 + 8*q + j]; }

    #pragma unroll 1
    for (int it = 0; it < MAX_ITER; ++it) {
        float nK = -K;
        float r  = __expf(0.125f * K);     // x ratio per t-step

        f32x4 acc[3][2];
        if (hh == 0) pipeAcc<0>(T0, nK, r, q, lane, d10b, tse0, tse15, Bs, acc);
        else         pipeAcc<1>(T0, nK, r, q, lane, d10b, tse0, tse15, Bs, acc);

        // ---- per-wave partial dots over its 2 quadrants ----
        float Ap[4];
        #pragma unroll
        for (int r2 = 0; r2 < 4; ++r2) Ap[r2] = __shfl(A, q*4 + r2);
        float SA[4], SK[4], ST[4];
        #pragma unroll
        for (int r2 = 0; r2 < 4; ++r2) { SA[r2]=0.f; SK[r2]=0.f; ST[r2]=0.f; }
        #pragma unroll
        for (int L = 0; L < 2; ++L)
            #pragma unroll
            for (int r2 = 0; r2 < 4; ++r2) {
                float Y0 = acc[0][L][r2], Y1 = acc[1][L][r2], Y2 = acc[2][L][r2];
                float rr = fmaf(Ap[r2], Y0, -dcreg[L][r2]);   // est - dc
                SA[r2] = fmaf(rr, Y0, SA[r2]);
                SK[r2] = fmaf(rr, Y1, SK[r2]);
                ST[r2] = fmaf(rr, Y2, ST[r2]);
            }
        #pragma unroll
        for (int r2 = 0; r2 < 4; ++r2)
            #pragma unroll
            for (int m = 1; m < 16; m <<= 1) {
                SA[r2] += __shfl_xor(SA[r2], m);
                SK[r2] += __shfl_xor(SK[r2], m);
                ST[r2] += __shfl_xor(ST[r2], m);
            }

        // ---- cross-pair sum: 12 scalars per (pair,hh,q), dbuf by it-parity ----
        if (n == 0) {
            float* xp = &xs[it & 1][pairid][hh][q][0];
            #pragma unroll
            for (int r2 = 0; r2 < 4; ++r2) {
                xp[r2]   = SA[r2];
                xp[4+r2] = SK[r2];
                xp[8+r2] = ST[r2];
            }
        }
        __syncthreads();
        {
            const float* xo = &xs[it & 1][pairid][1 - hh][q][0];
            #pragma unroll
            for (int r2 = 0; r2 < 4; ++r2) {
                SA[r2] += xo[r2];
                SK[r2] += xo[4+r2];
                ST[r2] += xo[8+r2];
            }
        }

        // ---- route: pixel p=n lives in group p>>2, slot p&3 ----
        int src = (n >> 2) * 16;
        float GA = 0.f, GK = 0.f, GT = 0.f;
        #pragma unroll
        for (int r2 = 0; r2 < 4; ++r2) {
            float tA = __shfl(SA[r2], src);
            float tK = __shfl(SK[r2], src);
            float tT = __shfl(ST[r2], src);
            if ((n & 3) == r2) { GA = tA; GK = tK; GT = tT; }
        }

        float gA = fmaf(rgA, A  - pA, cdc2 * GA)         + 2.0f * fminf(A,  0.f);
        float gK = fmaf(rgK, K  - pK, cdc2 * A * GK)     + 2.0f * fminf(K,  0.f);
        float gT = fmaf(rgT, T0 - pT, cdc2 * A * K * GT) + 2.0f * fminf(T0, 0.f);
        A  -= 0.1f * gA;
        K  -= 0.1f * gK;
        T0 -= 0.1f * gT;
    }

    if (hh == 0 && lane < 16) {
        out[mypix]          = A;
        out[NPIX + mypix]   = K;
        out[2*NPIX + mypix] = T0;
    }
}

// -------------------------------------------------------------- launch ------
extern "C" void kernel_launch(void* const* d_in, const int* in_sizes, int n_in,
                              void* d_out, int out_size, void* d_ws, size_t ws_size,
                              hipStream_t stream) {
    const float* ctc   = (const float*)d_in[0];
    const float* aif   = (const float*)d_in[1];
    const float* timev = (const float*)d_in[2];
    const float* eta   = (const float*)d_in[4];
    const float* lam   = (const float*)d_in[5];
    float* out = (float*)d_out;
    // ws layout: [0..4095]      f32x4 partials[256]
    //            [4096..6143]   float tshg[512]
    //            [8192..52223]  i32x4 Bg[NSLOT*64]
    f32x4* partials = (f32x4*)d_ws;
    float* tshg     = (float*)((char*)d_ws + 4096);
    i32x4* Bg       = (i32x4*)((char*)d_ws + 8192);

    k_prep<<<NPIX / 64, 256, 0, stream>>>(ctc, aif, timev, eta,
                                          tshg, Bg, partials);
    k_iter<<<NPIX / 32, 256, 0, stream>>>(ctc, lam, eta, tshg, Bg,
                                          partials, out);
}

// Round 4
// 105.964 us; speedup vs baseline: 1.1263x; 1.1263x over previous
//
#include <hip/hip_runtime.h>
#include <math.h>

#define T_IN 64
#define NPIX 16384
#define MAX_ITER 10
#define NSLOT 43

typedef _Float16 half8_t __attribute__((ext_vector_type(8)));
typedef __fp16   fp16x2  __attribute__((ext_vector_type(2)));
typedef float    f32x4   __attribute__((ext_vector_type(4)));
typedef int      i32x4   __attribute__((ext_vector_type(4)));

union H8 { half8_t v; fp16x2 h2[4]; i32x4 i4; };

__device__ __forceinline__ float rcp_fast(float x) { return __builtin_amdgcn_rcpf(x); }

__constant__ constexpr int NTMIN[16] = {0,0,0,0,0,1,1,1,1,2,2,2,2,3,3,3};
__constant__ constexpr int TOFS[16]  = {0,4,8,12,16,20,23,26,29,32,34,36,38,40,41,42};

// ---- field build for tile KT (compile-time KT -> all array idx constant) ----
template<int KT>
__device__ __forceinline__ void buildTile(float T0, float nK, float r, int q,
        const float (&d10b)[16], const float (&tse0)[8], const float (&tse15)[8],
        H8& F0h, H8& F1h, H8& F2h) {
    float  x[8];
    fp16x2 d1h[4];
    float  d10 = T0 - d10b[KT];
    const fp16x2 c1 = {(__fp16)0.25f, (__fp16)0.25f};
    const fp16x2 c2 = {(__fp16)0.50f, (__fp16)0.50f};
    const fp16x2 c3 = {(__fp16)0.75f, (__fp16)0.75f};
    bool arith = true;
    if constexpr (KT == 0 || KT == 15) {
        bool flat = (KT == 0) ? (q == 0) : (q == 3);   // clamped tsh samples
        if (flat) {
            arith = false;
            const float* te;
            if constexpr (KT == 0) te = tse0; else te = tse15;
            #pragma unroll
            for (int j = 0; j < 8; ++j) x[j] = __expf(nK * (T0 - te[j]));
            #pragma unroll
            for (int jj = 0; jj < 4; ++jj)
                d1h[jj] = __builtin_amdgcn_cvt_pkrtz(T0 - te[2*jj],
                                                     T0 - te[2*jj+1]);
        }
    }
    if (arith) {   // arithmetic tsh (step 0.125): split chains + pk d1h rebuild
        x[0] = __expf(nK * d10);
        x[4] = __expf(nK * (d10 - 0.5f));
        x[1] = x[0]*r; x[2] = x[1]*r; x[3] = x[2]*r;
        x[5] = x[4]*r; x[6] = x[5]*r; x[7] = x[6]*r;
        fp16x2 D0 = __builtin_amdgcn_cvt_pkrtz(d10, d10 - 0.125f);
        d1h[0] = D0;
        d1h[1] = D0 - c1;
        d1h[2] = D0 - c2;
        d1h[3] = D0 - c3;
    }
    #pragma unroll
    for (int jj = 0; jj < 4; ++jj) {
        float s1a = rcp_fast(1.0f + x[2*jj]);
        float s1b = rcp_fast(1.0f + x[2*jj+1]);
        fp16x2 sh = __builtin_amdgcn_cvt_pkrtz(s1a, s1b);
        fp16x2 eh = sh - sh*sh;                  // v_pk f16
        F0h.h2[jj] = sh;
        F1h.h2[jj] = eh * d1h[jj];
        F2h.h2[jj] = eh;
    }
}

// ---- stride-2 software pipeline: build tile KT+2, then MFMA tile KT ----
// Entered at KT = H (0 or 1); each wave of a pair covers one kt parity.
template<int KT>
struct Pipe2 {
    static __device__ __forceinline__ void run(float T0, float nK, float r, int q, int lane,
            const float (&d10b)[16], const float (&tse0)[8], const float (&tse15)[8],
            const i32x4* __restrict__ Bs,
            H8 (&F0p)[2], H8 (&F1p)[2], H8 (&F2p)[2],
            f32x4 (&acc)[3][4]) {
        constexpr int PB = (KT >> 1) & 1;       // ping-pong buffer of current tile
        if constexpr (KT + 2 < 16)
            buildTile<KT+2>(T0, nK, r, q, d10b, tse0, tse15,
                            F0p[PB^1], F1p[PB^1], F2p[PB^1]);
        const f32x4 Z = (f32x4){0.f, 0.f, 0.f, 0.f};
        #pragma unroll
        for (int nt = NTMIN[KT]; nt < 4; ++nt) {
            int slot = TOFS[KT] + nt - NTMIN[KT];
            H8 bh; bh.i4 = Bs[slot*64 + lane];
            if constexpr (KT < 2) {             // first tile for either parity
                acc[0][nt] = __builtin_amdgcn_mfma_f32_16x16x32_f16(F0p[PB].v, bh.v, Z, 0, 0, 0);
                acc[1][nt] = __builtin_amdgcn_mfma_f32_16x16x32_f16(F1p[PB].v, bh.v, Z, 0, 0, 0);
                acc[2][nt] = __builtin_amdgcn_mfma_f32_16x16x32_f16(F2p[PB].v, bh.v, Z, 0, 0, 0);
            } else {
                acc[0][nt] = __builtin_amdgcn_mfma_f32_16x16x32_f16(F0p[PB].v, bh.v, acc[0][nt], 0, 0, 0);
                acc[1][nt] = __builtin_amdgcn_mfma_f32_16x16x32_f16(F1p[PB].v, bh.v, acc[1][nt], 0, 0, 0);
                acc[2][nt] = __builtin_amdgcn_mfma_f32_16x16x32_f16(F2p[PB].v, bh.v, acc[2][nt], 0, 0, 0);
            }
        }
        if constexpr (KT + 2 < 16)
            Pipe2<KT+2>::run(T0, nK, r, q, lane, d10b, tse0, tse15, Bs, F0p, F1p, F2p, acc);
    }
};

template<int H>
__device__ __forceinline__ void pipeAcc(float T0, float nK, float r, int q, int lane,
        const float (&d10b)[16], const float (&tse0)[8], const float (&tse15)[8],
        const i32x4* __restrict__ Bs, f32x4 (&acc)[3][4]) {
    H8 F0p[2], F1p[2], F2p[2];
    buildTile<H>(T0, nK, r, q, d10b, tse0, tse15, F0p[0], F1p[0], F2p[0]);
    Pipe2<H>::run(T0, nK, r, q, lane, d10b, tse0, tse15, Bs, F0p, F1p, F2p, acc);
}

// ---- wave-pair acc exchange: H sends the components its partner finishes ----
// even wave (H=0) finishes pixel comps {0,1}, sends {2,3}; odd the reverse.
template<int H>
__device__ __forceinline__ void sendHalf(const f32x4 (&acc)[3][4],
        float2* __restrict__ xch, int pair, int lane) {
    constexpr int SB = 2 - 2*H;
    float2* xw = xch + ((pair*2 + H)*12)*64 + lane;   // value-major: lane stride 8B
    #pragma unroll
    for (int i = 0; i < 3; ++i)
        #pragma unroll
        for (int nt = 0; nt < 4; ++nt)
            xw[(i*4+nt)*64] = make_float2(acc[i][nt][SB], acc[i][nt][SB+1]);
}

template<int H>
__device__ __forceinline__ void finishDots(f32x4 (&acc)[3][4],
        const float2* __restrict__ xch, float (&Gtab)[2][16][4],
        int pair, int lane, int q, int n,
        const float (&dch)[4][2], float A) {
    constexpr int KB = 2*H;
    const float2* xr = xch + ((pair*2 + (1-H))*12)*64 + lane;
    #pragma unroll
    for (int i = 0; i < 3; ++i)
        #pragma unroll
        for (int nt = 0; nt < 4; ++nt) {
            float2 v = xr[(i*4+nt)*64];
            acc[i][nt][KB]   += v.x;
            acc[i][nt][KB+1] += v.y;
        }
    float Ap0 = __shfl(A, q*4 + KB);
    float Ap1 = __shfl(A, q*4 + KB + 1);
    float SA0=0.f,SK0=0.f,ST0=0.f, SA1=0.f,SK1=0.f,ST1=0.f;
    #pragma unroll
    for (int nt = 0; nt < 4; ++nt) {
        float Y0 = acc[0][nt][KB], Y1 = acc[1][nt][KB], Y2 = acc[2][nt][KB];
        float rr = fmaf(Ap0, Y0, -dch[nt][0]);           // est - dc
        SA0 = fmaf(rr, Y0, SA0); SK0 = fmaf(rr, Y1, SK0); ST0 = fmaf(rr, Y2, ST0);
        float y0 = acc[0][nt][KB+1], y1 = acc[1][nt][KB+1], y2 = acc[2][nt][KB+1];
        float r2 = fmaf(Ap1, y0, -dch[nt][1]);
        SA1 = fmaf(r2, y0, SA1); SK1 = fmaf(r2, y1, SK1); ST1 = fmaf(r2, y2, ST1);
    }
    #pragma unroll
    for (int m = 1; m < 16; m <<= 1) {
        SA0 += __shfl_xor(SA0, m); SK0 += __shfl_xor(SK0, m); ST0 += __shfl_xor(ST0, m);
        SA1 += __shfl_xor(SA1, m); SK1 += __shfl_xor(SK1, m); ST1 += __shfl_xor(ST1, m);
    }
    if (n == 0) {
        float* g = Gtab[pair][q*4 + KB];
        g[0] = SA0; g[1] = SK0; g[2] = ST0;
    }
    if (n == 1) {
        float* g = Gtab[pair][q*4 + KB + 1];
        g[0] = SA1; g[1] = SK1; g[2] = ST1;
    }
}

// ---------------------------------------------------------------- prep ------
// Unchanged from R16: phase A + C_dc/C_nn partials; B built once -> global ws.
__global__ __launch_bounds__(256, 1) void k_prep(
        const float* __restrict__ ctc,  const float* __restrict__ aif,
        const float* __restrict__ timev,const float* __restrict__ eta,
        float* __restrict__ tshg, i32x4* __restrict__ Bg,
        f32x4* __restrict__ partials) {
    __shared__ float tshs[512];
    __shared__ float aifos[512];
    __shared__ float a_s[64], t_s[64];
    __shared__ f32x4 red[4];

    const int tid  = threadIdx.x;
    const int lane = tid & 63;
    const int wid  = tid >> 6;
    const int q = lane >> 4, n = lane & 15;
    const int pixbase = blockIdx.x * 64 + wid * 16;
    const int mypix   = pixbase + n;

    if (tid < 64) { a_s[tid] = aif[tid]; t_s[tid] = timev[tid]; }
    float A  = eta[mypix];
    float K  = eta[NPIX + mypix];
    float T0 = eta[2*NPIX + mypix];
    __syncthreads();
    {
        float m5a = 0.2f * (a_s[0]+a_s[1]+a_s[2]+a_s[3]+a_s[4]);
        float t16;
        {   // t_os[16]: x = (16-3.5)/8 = 1.5625
            float xx = 1.5625f; int i0 = (int)xx; float f = xx - (float)i0;
            t16 = t_s[i0]*(1.0f-f) + t_s[i0+1]*f;
        }
        #pragma unroll
        for (int rep = 0; rep < 2; ++rep) {
            int i = tid + 256*rep;
            float x = ((float)i - 3.5f) * 0.125f;
            float ao, to;
            if (x <= 0.0f)       { ao = a_s[0]  - m5a; to = t_s[0];  }
            else if (x >= 63.0f) { ao = a_s[63] - m5a; to = t_s[63]; }
            else {
                int i0 = (int)x; float f = x - (float)i0;
                ao = (a_s[i0]-m5a)*(1.0f-f) + (a_s[i0+1]-m5a)*f;
                to = t_s[i0]*(1.0f-f) + t_s[i0+1]*f;
            }
            aifos[i] = ao;
            tshs[i]  = to - t16;
            if (blockIdx.x == 0) tshg[i] = to - t16;
        }
    }
    __syncthreads();

    // ---- B tile build: block s (< NSLOT) computes slot s, threads 0..63 ----
    if (blockIdx.x < NSLOT && tid < 64) {
        int slot = blockIdx.x, l = tid;
        int kt, nt;
        if (slot < 20)      { kt = slot >> 2; nt = slot & 3; }
        else if (slot < 32) { int s = slot - 20; int d3 = s / 3; kt = 5 + d3; nt = 1 + (s - 3*d3); }
        else if (slot < 40) { int s = slot - 32; kt = 9 + (s >> 1); nt = 2 + (s & 1); }
        else                { kt = 13 + (slot - 40); nt = 3; }
        int kbase = 32*kt + 8*(l >> 4);
        int m = 16 + 8 * (16*nt + (l & 15));   // m_d = 16+8d
        H8 bh;
        #pragma unroll
        for (int jj = 0; jj < 4; ++jj) {
            float v[2];
            #pragma unroll
            for (int h = 0; h < 2; ++h) {
                int k  = kbase + 2*jj + h;
                int ai = m - k;
                float s2 = 1.0f / (1.0f + __expf(-500.0f * tshs[k]));
                v[h] = (ai >= 0 && ai < 512) ? s2 * aifos[ai] * 0.125f : 0.0f;
            }
            bh.h2[jj] = (fp16x2){(__fp16)v[0], (__fp16)v[1]};   // RTN
        }
        Bg[slot*64 + l] = bh.i4;
    }

    // ---- ctc_dc partials ----
    float vs = 0.f;
    #pragma unroll
    for (int reg = 0; reg < 4; ++reg) {
        const float* cp = ctc + (pixbase + q*4 + reg) * T_IN;
        float m5 = 0.2f * (cp[0]+cp[1]+cp[2]+cp[3]+cp[4]);
        #pragma unroll
        for (int nt = 0; nt < 4; ++nt) {
            int d = nt*16 + n;
            float cc = cp[d] - m5;
            float cm = cp[(d > 0) ? d-1 : 0] - m5;
            float dc = (d == 0) ? cc : (0.4375f*cm + 0.5625f*cc);
            vs += dc * dc;
        }
    }
    {
        f32x4 pv = (f32x4){vs, 0.25f*A*A, 0.25f*K*K, 0.25f*T0*T0};
        #pragma unroll
        for (int m = 1; m < 64; m <<= 1) {
            pv.x += __shfl_xor(pv.x, m); pv.y += __shfl_xor(pv.y, m);
            pv.z += __shfl_xor(pv.z, m); pv.w += __shfl_xor(pv.w, m);
        }
        if (lane == 0) red[wid] = pv;
    }
    __syncthreads();
    if (tid == 0)
        partials[blockIdx.x] = red[0] + red[1] + red[2] + red[3];
}

// ---------------------------------------------------------------- iter ------
// R18: R16's kt-parity wave-pair loop VERBATIM, but 2 pairs per 256-thread
// block (32 px) and grid 512 -> 2 independent blocks/CU. LDS 70 KB < 80 KB.
// Co-resident waves now come from different blocks (disjoint barriers), so
// one block's exchange/barrier stalls are filled by the other's builds/MFMAs.
__global__ __launch_bounds__(256, 2) void k_iter(
        const float* __restrict__ ctc,  const float* __restrict__ lam,
        const float* __restrict__ eta,  const float* __restrict__ tshg,
        const i32x4* __restrict__ Bg,   const f32x4* __restrict__ partials,
        float* __restrict__ out) {
    __shared__ i32x4 Bs[NSLOT * 64];   // 43 KB
    __shared__ float tshs[512];        // 2 KB
    __shared__ float2 xch[2*2*12*64];  // 24 KB acc exchange
    __shared__ float Gtab[2][16][4];   // per-pair per-pixel gradients

    const int tid  = threadIdx.x;
    const int lane = tid & 63;
    const int wid  = tid >> 6;         // 0..3
    const int hh   = wid & 1;          // kt parity handled by this wave
    const int pair = wid >> 1;         // pixel group 0..1
    const int q = lane >> 4, n = lane & 15;
    const int pixbase = blockIdx.x * 32 + pair * 16;
    const int mypix   = pixbase + n;

    // ---- stage B + tshs into LDS ----
    for (int idx = tid; idx < NSLOT * 64; idx += 256) Bs[idx] = Bg[idx];
    tshs[tid] = tshg[tid];
    tshs[tid + 256] = tshg[tid + 256];

    float A  = eta[mypix];
    float K  = eta[NPIX + mypix];
    float T0 = eta[2*NPIX + mypix];
    const float pA = A, pK = K, pT = T0;

    // ctc_dc rows this wave finishes: dch[nt][j] = dc[p=q*4+2*hh+j][d=nt*16+n]
    float dch[4][2];
    #pragma unroll
    for (int j = 0; j < 2; ++j) {
        const float* cp = ctc + (pixbase + q*4 + 2*hh + j) * T_IN;
        float m5 = 0.2f * (cp[0]+cp[1]+cp[2]+cp[3]+cp[4]);
        #pragma unroll
        for (int nt = 0; nt < 4; ++nt) {
            int d = nt*16 + n;
            float cc = cp[d] - m5;
            float cm = cp[(d > 0) ? d-1 : 0] - m5;
            dch[nt][j] = (d == 0) ? cc : (0.4375f*cm + 0.5625f*cc);
        }
    }

    // ---- reduce the 256 completed partials ----
    f32x4 tot = partials[lane] + partials[64+lane] + partials[128+lane]
              + partials[192+lane];
    #pragma unroll
    for (int m = 1; m < 64; m <<= 1) {
        tot.x += __shfl_xor(tot.x, m); tot.y += __shfl_xor(tot.y, m);
        tot.z += __shfl_xor(tot.z, m); tot.w += __shfl_xor(tot.w, m);
    }
    float spl;
    {
        float xl = lam[0];
        spl = (xl > 0.0f) ? (xl + log1pf(__expf(-xl))) : log1pf(__expf(xl));
    }
    const float cdc2 = 2.0f / tot.x;
    const float rgA  = 2.0f * spl / tot.y;
    const float rgK  = 2.0f * spl / tot.z;
    const float rgT  = 2.0f * spl / tot.w;

    __syncthreads();   // Bs / tshs visible

    // ---- hoist tsh seeds (iteration-invariant, per-lane q) ----
    float  d10b[16];           // chain seeds: tsh[32kt+8q]
    float  tse0[8], tse15[8];  // full f32 for the edge path
    #pragma unroll
    for (int kt = 0; kt < 16; ++kt) d10b[kt] = tshs[32*kt + 8*q];
    #pragma unroll
    for (int j = 0; j < 8; ++j) { tse0[j] = tshs[8*q + j]; tse15[j] = tshs[480 + 8*q + j]; }

    #pragma unroll 1
    for (int it = 0; it < MAX_ITER; ++it) {
        float nK = -K;
        float r  = __expf(0.125f * K);     // x ratio per t-step

        f32x4 acc[3][4];
        if (hh == 0) {
            pipeAcc<0>(T0, nK, r, q, lane, d10b, tse0, tse15, Bs, acc);
            sendHalf<0>(acc, xch, pair, lane);
        } else {
            pipeAcc<1>(T0, nK, r, q, lane, d10b, tse0, tse15, Bs, acc);
            sendHalf<1>(acc, xch, pair, lane);
        }
        __syncthreads();
        if (hh == 0) finishDots<0>(acc, xch, Gtab, pair, lane, q, n, dch, A);
        else         finishDots<1>(acc, xch, Gtab, pair, lane, q, n, dch, A);
        __syncthreads();

        const float GA = Gtab[pair][n][0];
        const float GK = Gtab[pair][n][1];
        const float GT = Gtab[pair][n][2];
        float gA = fmaf(rgA, A  - pA, cdc2 * GA)         + 2.0f * fminf(A,  0.f);
        float gK = fmaf(rgK, K  - pK, cdc2 * A * GK)     + 2.0f * fminf(K,  0.f);
        float gT = fmaf(rgT, T0 - pT, cdc2 * A * K * GT) + 2.0f * fminf(T0, 0.f);
        A  -= 0.1f * gA;
        K  -= 0.1f * gK;
        T0 -= 0.1f * gT;
    }

    if (hh == 0 && lane < 16) {
        out[mypix]          = A;
        out[NPIX + mypix]   = K;
        out[2*NPIX + mypix] = T0;
    }
}

// -------------------------------------------------------------- launch ------
extern "C" void kernel_launch(void* const* d_in, const int* in_sizes, int n_in,
                              void* d_out, int out_size, void* d_ws, size_t ws_size,
                              hipStream_t stream) {
    const float* ctc   = (const float*)d_in[0];
    const float* aif   = (const float*)d_in[1];
    const float* timev = (const float*)d_in[2];
    const float* eta   = (const float*)d_in[4];
    const float* lam   = (const float*)d_in[5];
    float* out = (float*)d_out;
    // ws layout: [0..4095]      f32x4 partials[256]
    //            [4096..6143]   float tshg[512]
    //            [8192..52223]  i32x4 Bg[NSLOT*64]
    f32x4* partials = (f32x4*)d_ws;
    float* tshg     = (float*)((char*)d_ws + 4096);
    i32x4* Bg       = (i32x4*)((char*)d_ws + 8192);

    k_prep<<<NPIX / 64, 256, 0, stream>>>(ctc, aif, timev, eta,
                                          tshg, Bg, partials);
    k_iter<<<NPIX / 32, 256, 0, stream>>>(ctc, lam, eta, tshg, Bg,
                                          partials, out);
}